// Round 1
// baseline (21690.524 us; speedup 1.0000x reference)
//
#include <hip/hip_runtime.h>
#include <hip/hip_bf16.h>
#include <math.h>

// Problem constants (match reference)
#define LAYERS 8
#define DMODEL 1024
#define NHEAD  16
#define HEADD  64
#define SEQ    1024
#define BATCH  2
#define VOCAB  32000
#define ROWS   (BATCH * SEQ)   // 2048 token rows

// ---------------------------------------------------------------------------
// Embedding: x[b,t,:] = tok_emb[idx[b,t]] + pos_emb[t]
// grid = ROWS, block = 256 (one float4 per thread; D=1024)
// ---------------------------------------------------------------------------
__global__ __launch_bounds__(256) void embed_kernel(
    const int* __restrict__ idx, const float* __restrict__ tok,
    const float* __restrict__ pos, float* __restrict__ x)
{
    const int row = blockIdx.x;          // b*SEQ + t
    const int t   = row & (SEQ - 1);
    const int token = idx[row];
    const int c = threadIdx.x * 4;
    const float4 a = *(const float4*)&tok[(size_t)token * DMODEL + c];
    const float4 p = *(const float4*)&pos[(size_t)t * DMODEL + c];
    float4 o;
    o.x = a.x + p.x; o.y = a.y + p.y; o.z = a.z + p.z; o.w = a.w + p.w;
    *(float4*)&x[(size_t)row * DMODEL + c] = o;
}

// ---------------------------------------------------------------------------
// LayerNorm: out = (x - mean)*rsqrt(var+eps)*g + b   (row-wise, D=1024)
// grid = ROWS, block = 256
// ---------------------------------------------------------------------------
__global__ __launch_bounds__(256) void ln_kernel(
    const float* __restrict__ x, const float* __restrict__ g,
    const float* __restrict__ b, float* __restrict__ o)
{
    const int row = blockIdx.x;
    const int tid = threadIdx.x;
    const int c = tid * 4;
    const float* xr = x + (size_t)row * DMODEL;
    const float4 v = *(const float4*)&xr[c];
    float s = v.x + v.y + v.z + v.w;
    float q = v.x*v.x + v.y*v.y + v.z*v.z + v.w*v.w;
    #pragma unroll
    for (int off = 32; off > 0; off >>= 1) {
        s += __shfl_xor(s, off);
        q += __shfl_xor(q, off);
    }
    __shared__ float rs[4], rq[4];
    if ((tid & 63) == 0) { rs[tid >> 6] = s; rq[tid >> 6] = q; }
    __syncthreads();
    s = rs[0] + rs[1] + rs[2] + rs[3];
    q = rq[0] + rq[1] + rq[2] + rq[3];
    const float mean = s * (1.0f / DMODEL);
    const float var  = q * (1.0f / DMODEL) - mean * mean;
    const float rstd = rsqrtf(var + 1e-5f);
    const float4 gv = *(const float4*)&g[c];
    const float4 bv = *(const float4*)&b[c];
    float4 ov;
    ov.x = (v.x - mean) * rstd * gv.x + bv.x;
    ov.y = (v.y - mean) * rstd * gv.y + bv.y;
    ov.z = (v.z - mean) * rstd * gv.z + bv.z;
    ov.w = (v.w - mean) * rstd * gv.w + bv.w;
    *(float4*)&o[(size_t)row * DMODEL + c] = ov;
}

// ---------------------------------------------------------------------------
// FP32 tiled GEMM: C[M,N] = epilogue(A[M,K] @ B[K,N] + bias [+ res])
// 128x128 tile, BK=16, 256 threads, 8x8 microtile per thread.
// EPI: 0 = +bias, 1 = +bias+residual, 2 = gelu(+bias), 3 = plain
// All M,N multiples of 128; K multiple of 16 (true for every call here).
// NOTE: res/C may alias (in-place residual) -> no __restrict__ on them.
// ---------------------------------------------------------------------------
#define GBM 128
#define GBN 128
#define GBK 16

__device__ __forceinline__ float gelu_exact(float v) {
    return 0.5f * v * (1.0f + erff(v * 0.70710678118654752f));
}

template <int EPI>
__global__ __launch_bounds__(256) void gemm128(
    const float* __restrict__ A, const float* __restrict__ Bm,
    const float* __restrict__ bias, const float* res,
    float* C, int M, int N, int K)
{
    __shared__ float As[GBK][GBM];   // transposed A tile: As[k][m]
    __shared__ float Bs[GBK][GBN];

    const int tid = threadIdx.x;
    const int rowBase = blockIdx.y * GBM;
    const int colBase = blockIdx.x * GBN;
    const int tr = tid >> 4, tc = tid & 15;     // 16x16 thread grid
    const int r0 = tr * 8,  c0 = tc * 8;        // microtile origin

    // A tile loads: 128 rows x 16 k; thread loads rows (aRow, aRow+64), k aCol..aCol+3
    const int aRow = tid >> 2, aCol = (tid & 3) << 2;
    // B tile loads: 16 rows x 128 cols; thread loads rows (bRow, bRow+8), cols bCol..bCol+3
    const int bRow = tid >> 5, bCol = (tid & 31) << 2;

    const float* Aptr = A + (size_t)(rowBase + aRow) * K + aCol;
    const float* Bptr = Bm + (size_t)bRow * N + colBase + bCol;

    float acc[8][8] = {};

    for (int k0 = 0; k0 < K; k0 += GBK) {
        const float4 a0 = *(const float4*)(Aptr);
        const float4 a1 = *(const float4*)(Aptr + (size_t)64 * K);
        const float4 b0 = *(const float4*)(Bptr);
        const float4 b1 = *(const float4*)(Bptr + (size_t)8 * N);
        __syncthreads();   // previous tile fully consumed
        As[aCol + 0][aRow] = a0.x; As[aCol + 1][aRow] = a0.y;
        As[aCol + 2][aRow] = a0.z; As[aCol + 3][aRow] = a0.w;
        As[aCol + 0][aRow + 64] = a1.x; As[aCol + 1][aRow + 64] = a1.y;
        As[aCol + 2][aRow + 64] = a1.z; As[aCol + 3][aRow + 64] = a1.w;
        *(float4*)&Bs[bRow][bCol]     = b0;
        *(float4*)&Bs[bRow + 8][bCol] = b1;
        __syncthreads();
        #pragma unroll
        for (int kk = 0; kk < GBK; ++kk) {
            float a[8], b[8];
            *(float4*)&a[0] = *(const float4*)&As[kk][r0];
            *(float4*)&a[4] = *(const float4*)&As[kk][r0 + 4];
            *(float4*)&b[0] = *(const float4*)&Bs[kk][c0];
            *(float4*)&b[4] = *(const float4*)&Bs[kk][c0 + 4];
            #pragma unroll
            for (int i = 0; i < 8; ++i)
                #pragma unroll
                for (int j = 0; j < 8; ++j)
                    acc[i][j] = fmaf(a[i], b[j], acc[i][j]);
        }
        Aptr += GBK;
        Bptr += (size_t)GBK * N;
    }

    // epilogue
    #pragma unroll
    for (int i = 0; i < 8; ++i) {
        const size_t row = (size_t)(rowBase + r0 + i);
        #pragma unroll
        for (int jj = 0; jj < 2; ++jj) {
            const int col = colBase + c0 + jj * 4;
            float4 v;
            v.x = acc[i][jj*4+0]; v.y = acc[i][jj*4+1];
            v.z = acc[i][jj*4+2]; v.w = acc[i][jj*4+3];
            if (EPI != 3) {
                const float4 bb = *(const float4*)&bias[col];
                v.x += bb.x; v.y += bb.y; v.z += bb.z; v.w += bb.w;
            }
            if (EPI == 1) {
                const float4 rv = *(const float4*)&res[row * N + col];
                v.x += rv.x; v.y += rv.y; v.z += rv.z; v.w += rv.w;
            }
            if (EPI == 2) {
                v.x = gelu_exact(v.x); v.y = gelu_exact(v.y);
                v.z = gelu_exact(v.z); v.w = gelu_exact(v.w);
            }
            *(float4*)&C[row * N + col] = v;
        }
    }
}

// ---------------------------------------------------------------------------
// Attention: one block per (b, head, query). qkv layout [B, T, 3, H, HD].
// Scores staged in LDS (4 KB), two-pass softmax, no causal mask (faithful).
// Output written directly in [B, T, D] layout (d = h*64 + hd).
// ---------------------------------------------------------------------------
__global__ __launch_bounds__(256) void attn_kernel(
    const float* __restrict__ qkv, float* __restrict__ y)
{
    const int bid = blockIdx.x;          // b*H*T + h*T + tq
    const int tq  = bid & (SEQ - 1);
    const int bh  = bid >> 10;
    const int hh  = bh & (NHEAD - 1);
    const int b   = bh >> 4;
    const int tid = threadIdx.x;
    const float* base = qkv + (size_t)b * SEQ * (3 * DMODEL);

    __shared__ float qs[HEADD];
    __shared__ float sc[SEQ];
    __shared__ float red[8];
    __shared__ float yred[4][HEADD];

    if (tid < 16)
        *(float4*)&qs[tid * 4] =
            *(const float4*)&base[(size_t)tq * (3*DMODEL) + hh * HEADD + tid * 4];
    __syncthreads();

    // scores
    for (int k = tid; k < SEQ; k += 256) {
        const float* kr = base + (size_t)k * (3*DMODEL) + DMODEL + hh * HEADD;
        float s = 0.f;
        #pragma unroll
        for (int d = 0; d < HEADD; d += 4) {
            const float4 kv = *(const float4*)&kr[d];
            s = fmaf(kv.x, qs[d],     s);
            s = fmaf(kv.y, qs[d + 1], s);
            s = fmaf(kv.z, qs[d + 2], s);
            s = fmaf(kv.w, qs[d + 3], s);
        }
        sc[k] = s * 0.125f;              // 1/sqrt(64)
    }
    __syncthreads();

    // max
    float m = -INFINITY;
    for (int k = tid; k < SEQ; k += 256) m = fmaxf(m, sc[k]);
    #pragma unroll
    for (int off = 32; off > 0; off >>= 1) m = fmaxf(m, __shfl_xor(m, off));
    if ((tid & 63) == 0) red[tid >> 6] = m;
    __syncthreads();
    m = fmaxf(fmaxf(red[0], red[1]), fmaxf(red[2], red[3]));

    // exp + sum (each thread touches only its own sc[k] subset -> race-free)
    float s = 0.f;
    for (int k = tid; k < SEQ; k += 256) {
        const float p = expf(sc[k] - m);
        sc[k] = p;
        s += p;
    }
    #pragma unroll
    for (int off = 32; off > 0; off >>= 1) s += __shfl_xor(s, off);
    if ((tid & 63) == 0) red[4 + (tid >> 6)] = s;   // distinct slots, no race
    __syncthreads();
    const float inv = 1.0f / (red[4] + red[5] + red[6] + red[7]);

    // y[d] = sum_k p[k] * v[k][d]; 256 threads = 64 dims x 4 key groups
    const int d = tid & 63, g = tid >> 6;
    const float* vbase = base + 2 * DMODEL + hh * HEADD + d;
    float acc = 0.f;
    const int k0 = g * 256;
    for (int k = k0; k < k0 + 256; ++k)
        acc = fmaf(sc[k], vbase[(size_t)k * (3*DMODEL)], acc);
    yred[g][d] = acc;
    __syncthreads();
    if (tid < 64) {
        const float o = (yred[0][tid] + yred[1][tid] + yred[2][tid] + yred[3][tid]) * inv;
        y[((size_t)(b * SEQ + tq)) * DMODEL + hh * HEADD + tid] = o;
    }
}

// ---------------------------------------------------------------------------
// Loss: per-row log-softmax over V=32000 + NLL at target, mean over rows.
// grid = ROWS, block = 256. Loss slot zeroed by zero_loss first.
// ---------------------------------------------------------------------------
__global__ void zero_loss(float* p) { *p = 0.f; }

__global__ __launch_bounds__(256) void loss_kernel(
    const float* __restrict__ logits, const int* __restrict__ targets,
    float* __restrict__ loss)
{
    const int r = blockIdx.x;
    const int tid = threadIdx.x;
    const float* row = logits + (size_t)r * VOCAB;
    __shared__ float red[8];

    float m = -INFINITY;
    for (int i = tid; i < VOCAB; i += 256) m = fmaxf(m, row[i]);
    #pragma unroll
    for (int off = 32; off > 0; off >>= 1) m = fmaxf(m, __shfl_xor(m, off));
    if ((tid & 63) == 0) red[tid >> 6] = m;
    __syncthreads();
    m = fmaxf(fmaxf(red[0], red[1]), fmaxf(red[2], red[3]));

    float s = 0.f;
    for (int i = tid; i < VOCAB; i += 256) s += expf(row[i] - m);
    #pragma unroll
    for (int off = 32; off > 0; off >>= 1) s += __shfl_xor(s, off);
    if ((tid & 63) == 0) red[4 + (tid >> 6)] = s;
    __syncthreads();
    s = red[4] + red[5] + red[6] + red[7];

    if (tid == 0) {
        const int t = targets[r];
        const float nll = -(row[t] - m - logf(s));
        atomicAdd(loss, nll * (1.0f / (float)ROWS));
    }
}

// ---------------------------------------------------------------------------
// Launcher.
// Workspace layout (floats):
//   x   @ 0         : ROWS*D            = 2,097,152  (8 MB)  residual stream
//   h   @ 2097152   : ROWS*D            = 2,097,152  (8 MB)  LN out / attn out
//   qkv @ 4194304   : ROWS*3D           = 6,291,456  (24 MB) \ overlaid:
//   ff  @ 4194304   : ROWS*4D           = 8,388,608  (32 MB) / qkv dead by then
// Total: 48 MB.
// ---------------------------------------------------------------------------
extern "C" void kernel_launch(void* const* d_in, const int* in_sizes, int n_in,
                              void* d_out, int out_size, void* d_ws, size_t ws_size,
                              hipStream_t stream)
{
    const int*   idx     = (const int*)  d_in[0];
    const int*   targets = (const int*)  d_in[1];
    const float* tok_emb = (const float*)d_in[2];
    const float* pos_emb = (const float*)d_in[3];
    const float* ln1_s   = (const float*)d_in[4];
    const float* ln1_b   = (const float*)d_in[5];
    const float* qkv_w   = (const float*)d_in[6];
    const float* qkv_b   = (const float*)d_in[7];
    const float* proj_w  = (const float*)d_in[8];
    const float* proj_b  = (const float*)d_in[9];
    const float* ln2_s   = (const float*)d_in[10];
    const float* ln2_b   = (const float*)d_in[11];
    const float* fc1_w   = (const float*)d_in[12];
    const float* fc1_b   = (const float*)d_in[13];
    const float* fc2_w   = (const float*)d_in[14];
    const float* fc2_b   = (const float*)d_in[15];
    const float* lnf_s   = (const float*)d_in[16];
    const float* lnf_b   = (const float*)d_in[17];
    const float* head_w  = (const float*)d_in[18];

    float* logits = (float*)d_out;
    float* loss   = logits + (size_t)ROWS * VOCAB;

    float* ws  = (float*)d_ws;
    float* x   = ws;
    float* h   = ws + 2097152;
    float* qkv = ws + 4194304;
    float* ff  = ws + 4194304;   // overlaid with qkv (qkv dead before ff written)

    embed_kernel<<<ROWS, 256, 0, stream>>>(idx, tok_emb, pos_emb, x);

    for (int l = 0; l < LAYERS; ++l) {
        // LN1 -> h
        ln_kernel<<<ROWS, 256, 0, stream>>>(x, ln1_s + l * DMODEL, ln1_b + l * DMODEL, h);
        // qkv = h @ qkv_w[l] + qkv_b[l]
        gemm128<0><<<dim3(3 * DMODEL / GBN, ROWS / GBM), 256, 0, stream>>>(
            h, qkv_w + (size_t)l * DMODEL * 3 * DMODEL, qkv_b + (size_t)l * 3 * DMODEL,
            nullptr, qkv, ROWS, 3 * DMODEL, DMODEL);
        // attention -> h (reuses LN1 buffer; dead after qkv GEMM)
        attn_kernel<<<BATCH * NHEAD * SEQ, 256, 0, stream>>>(qkv, h);
        // x = x + h @ proj_w[l] + proj_b[l]
        gemm128<1><<<dim3(DMODEL / GBN, ROWS / GBM), 256, 0, stream>>>(
            h, proj_w + (size_t)l * DMODEL * DMODEL, proj_b + (size_t)l * DMODEL,
            x, x, ROWS, DMODEL, DMODEL);
        // LN2 -> h
        ln_kernel<<<ROWS, 256, 0, stream>>>(x, ln2_s + l * DMODEL, ln2_b + l * DMODEL, h);
        // ff = gelu(h @ fc1_w[l] + fc1_b[l])
        gemm128<2><<<dim3(4 * DMODEL / GBN, ROWS / GBM), 256, 0, stream>>>(
            h, fc1_w + (size_t)l * DMODEL * 4 * DMODEL, fc1_b + (size_t)l * 4 * DMODEL,
            nullptr, ff, ROWS, 4 * DMODEL, DMODEL);
        // x = x + ff @ fc2_w[l] + fc2_b[l]
        gemm128<1><<<dim3(DMODEL / GBN, ROWS / GBM), 256, 0, stream>>>(
            ff, fc2_w + (size_t)l * 4 * DMODEL * DMODEL, fc2_b + (size_t)l * DMODEL,
            x, x, ROWS, DMODEL, 4 * DMODEL);
    }

    // final LN -> h
    ln_kernel<<<ROWS, 256, 0, stream>>>(x, lnf_s, lnf_b, h);
    // logits = h @ head_w  (no bias)
    gemm128<3><<<dim3(VOCAB / GBN, ROWS / GBM), 256, 0, stream>>>(
        h, head_w, nullptr, nullptr, logits, ROWS, VOCAB, DMODEL);

    // loss
    zero_loss<<<1, 1, 0, stream>>>(loss);
    loss_kernel<<<ROWS, 256, 0, stream>>>(logits, targets, loss);
}